// Round 1
// baseline (1026.742 us; speedup 1.0000x reference)
//
#include <hip/hip_runtime.h>
#include <cmath>

#define NTOK 64
#define DIM  128
#define OV   32
#define NB   512

// smem layout (float offsets)
#define SE_OFF   0        // [64][132] se
#define SE_LD    132
#define WT_OFF   8448     // phase1 staging: [128][36]
#define WT_LD    36
#define WTC_OFF  8448     // tile32 staging: [32][68]
#define WTC_LD   68
#define KCL_OFF  10624    // [64][36] k chunk
#define QCL_OFF  12928    // [64][36] q chunk
#define VLS_OFF  12928    // [64][36] v (after logits, qcL dead)
#define KQ_LD    36
#define WLS_OFF  8448     // [64][68] attention weights (after logits)
#define WLS_LD   68
#define SMEM_FLOATS 15232 // 60928 bytes

// Computes out[n][c] = opt_leaky( bias[c] + sum_d seL[n][d] * W[c][d] ), c in [0,32)
// W rows have stride DIM. outL has leading dim KQ_LD. Uses wtc as staging.
// Thread map: n = ng*4 + i (i<4), c = cg + 16*j (j<2).
__device__ __forceinline__ void tile32_gemm(
    const float* seL, const float* __restrict__ W,
    const float* __restrict__ bias, float* outL, float* wtc,
    int tid, int ng, int cg, bool act)
{
    float acc[4][2];
#pragma unroll
    for (int j = 0; j < 2; j++) {
        float bv = bias[cg + 16*j];
#pragma unroll
        for (int i = 0; i < 4; i++) acc[i][j] = bv;
    }
    for (int dsub = 0; dsub < DIM; dsub += 64) {
        __syncthreads();   // protect wtc from previous readers
#pragma unroll
        for (int r = 0; r < 2; r++) {
            int f4  = tid + 256*r;          // 0..511
            int row = f4 >> 4;              // 0..31
            int c4  = (f4 & 15) * 4;        // 0..60
            float4 v = *(const float4*)(W + (size_t)row*DIM + dsub + c4);
            *(float4*)(wtc + row*WTC_LD + c4) = v;
        }
        __syncthreads();
#pragma unroll
        for (int d4 = 0; d4 < 64; d4 += 4) {
            float4 a4[4];
#pragma unroll
            for (int i = 0; i < 4; i++)
                a4[i] = *(const float4*)(seL + (ng*4+i)*SE_LD + dsub + d4);
#pragma unroll
            for (int t = 0; t < 4; t++) {
#pragma unroll
                for (int j = 0; j < 2; j++) {
                    float wv = wtc[(cg+16*j)*WTC_LD + d4 + t];
#pragma unroll
                    for (int i = 0; i < 4; i++)
                        acc[i][j] = fmaf(((const float*)&a4[i])[t], wv, acc[i][j]);
                }
            }
        }
    }
#pragma unroll
    for (int i = 0; i < 4; i++) {
#pragma unroll
        for (int j = 0; j < 2; j++) {
            float v = acc[i][j];
            if (act) v = (v >= 0.f) ? v : 0.01f*v;
            outL[(ng*4+i)*KQ_LD + cg + 16*j] = v;
        }
    }
    // no trailing sync: caller's next barrier publishes outL
}

template<int IN>
__global__ __launch_bounds__(256)
void attn_stage_kernel(
    const float* __restrict__ x,   // [NB][NTOK][IN]
    const float* __restrict__ Ew,  // [4][DIM][IN]
    const float* __restrict__ Eb,  // [4][DIM]
    const float* __restrict__ Kw,  // [4][DIM][DIM]
    const float* __restrict__ Kb,  // [4][DIM]
    const float* __restrict__ Qw,  // [4][DIM][DIM]
    const float* __restrict__ Qb,  // [4][DIM]
    const float* __restrict__ Vw,  // [4][OV][DIM]
    const float* __restrict__ Vb,  // [4][OV]
    float* __restrict__ w_out,     // [4][NB][NTOK][NTOK]
    float* __restrict__ x_out)     // [NB][NTOK][4*OV]
{
    __shared__ float smem[SMEM_FLOATS];
    const int tid = threadIdx.x;
    const int b = blockIdx.x >> 2;   // 4 consecutive blocks share states[b] in L2
    const int h = blockIdx.x & 3;
    const int ng = tid >> 4;         // rows n = ng*4 + i
    const int cg = tid & 15;         // col group

    float* seL = smem + SE_OFF;

    // ---------------- Phase 1: se = leaky(x[b] @ Ew[h]^T + Eb[h]) ----------------
    {
        float* wt = smem + WT_OFF;
        float acc[4][8];   // n = ng*4+i, d = cg + 16*j
#pragma unroll
        for (int j = 0; j < 8; j++) {
            float bv = Eb[h*DIM + cg + 16*j];
#pragma unroll
            for (int i = 0; i < 4; i++) acc[i][j] = bv;
        }
        const float* xb  = x  + (size_t)b * NTOK * IN;
        const float* ewh = Ew + (size_t)h * DIM * IN;
        for (int kk0 = 0; kk0 < IN; kk0 += 32) {
            __syncthreads();
#pragma unroll
            for (int r = 0; r < 4; r++) {
                int f4  = tid + 256*r;        // 0..1023
                int row = f4 >> 3;            // 0..127
                int c4  = (f4 & 7) * 4;       // 0..28
                float4 v = *(const float4*)(ewh + (size_t)row*IN + kk0 + c4);
                *(float4*)(wt + row*WT_LD + c4) = v;
            }
            __syncthreads();
#pragma unroll
            for (int k4 = 0; k4 < 32; k4 += 4) {
                float4 a4[4];
#pragma unroll
                for (int i = 0; i < 4; i++)
                    a4[i] = *(const float4*)(xb + (size_t)(ng*4+i)*IN + kk0 + k4);
#pragma unroll
                for (int t = 0; t < 4; t++) {
#pragma unroll
                    for (int j = 0; j < 8; j++) {
                        float wv = wt[(cg+16*j)*WT_LD + k4 + t];
#pragma unroll
                        for (int i = 0; i < 4; i++)
                            acc[i][j] = fmaf(((const float*)&a4[i])[t], wv, acc[i][j]);
                    }
                }
            }
        }
#pragma unroll
        for (int i = 0; i < 4; i++) {
#pragma unroll
            for (int j = 0; j < 8; j++) {
                float v = acc[i][j];
                v = (v >= 0.f) ? v : 0.01f*v;
                seL[(ng*4+i)*SE_LD + cg + 16*j] = v;
            }
        }
        __syncthreads();
    }

    // ---------------- Phase 2: logits = (se Kw^T+b)(se Qw^T+b)^T style, chunked ----------------
    float lacc[4][4];   // n = ng*4+i, m = cg + 16*jj
#pragma unroll
    for (int i = 0; i < 4; i++)
#pragma unroll
        for (int jj = 0; jj < 4; jj++) lacc[i][jj] = 0.f;
    {
        float* wtc = smem + WTC_OFF;
        float* kcL = smem + KCL_OFF;
        float* qcL = smem + QCL_OFF;
        const float* kwh = Kw + (size_t)h*DIM*DIM;
        const float* qwh = Qw + (size_t)h*DIM*DIM;
        for (int ec = 0; ec < 4; ec++) {
            // k chunk: k[n][ec*32 + c]
            tile32_gemm(seL, kwh + (size_t)ec*32*DIM, Kb + h*DIM + ec*32, kcL, wtc, tid, ng, cg, false);
            // q chunk (its internal barriers also publish kcL)
            tile32_gemm(seL, qwh + (size_t)ec*32*DIM, Qb + h*DIM + ec*32, qcL, wtc, tid, ng, cg, false);
            __syncthreads();   // publish qcL
            // partial logits over this e-chunk
#pragma unroll
            for (int el4 = 0; el4 < 32; el4 += 4) {
                float4 q4[4], k4v[4];
#pragma unroll
                for (int i = 0; i < 4; i++)
                    q4[i] = *(const float4*)(qcL + (ng*4+i)*KQ_LD + el4);
#pragma unroll
                for (int jj = 0; jj < 4; jj++)
                    k4v[jj] = *(const float4*)(kcL + (cg+16*jj)*KQ_LD + el4);
#pragma unroll
                for (int t = 0; t < 4; t++)
#pragma unroll
                    for (int i = 0; i < 4; i++)
#pragma unroll
                        for (int jj = 0; jj < 4; jj++)
                            lacc[i][jj] = fmaf(((const float*)&q4[i])[t],
                                               ((const float*)&k4v[jj])[t], lacc[i][jj]);
            }
        }
        // ---------------- v = leaky(se Vw^T + Vb) into VLS (over dead qcL) ----------------
        tile32_gemm(seL, Vw + (size_t)h*OV*DIM, Vb + h*OV, smem + VLS_OFF, wtc, tid, ng, cg, true);
    }

    // ---------------- Phase 3: softmax -> wls + w_out ----------------
    {
        float* wls = smem + WLS_OFF;
        __syncthreads();   // all logits reads + v writes done before wls overwrites wtc/kcL
        const float scale = 0.08838834764831845f;  // 1/sqrt(128)
#pragma unroll
        for (int i = 0; i < 4; i++)
#pragma unroll
            for (int jj = 0; jj < 4; jj++)
                wls[(ng*4+i)*WLS_LD + cg + 16*jj] = lacc[i][jj] * scale;
        __syncthreads();
        // 4 lanes per row: lane t -> (n = t>>2, g = t&3), 16 values each
        const int n = tid >> 2, g = tid & 3;
        float vals[16];
        float mx = -1e30f;
#pragma unroll
        for (int q = 0; q < 4; q++) {
            float4 v = *(const float4*)(wls + n*WLS_LD + g*16 + q*4);
            vals[q*4+0] = v.x; vals[q*4+1] = v.y; vals[q*4+2] = v.z; vals[q*4+3] = v.w;
            mx = fmaxf(mx, fmaxf(fmaxf(v.x, v.y), fmaxf(v.z, v.w)));
        }
        mx = fmaxf(mx, __shfl_xor(mx, 1, 4));
        mx = fmaxf(mx, __shfl_xor(mx, 2, 4));
        float s = 0.f;
#pragma unroll
        for (int q = 0; q < 16; q++) { vals[q] = expf(vals[q] - mx); s += vals[q]; }
        s += __shfl_xor(s, 1, 4);
        s += __shfl_xor(s, 2, 4);
        float inv = 1.0f / s;
        float* wrow = w_out + (((size_t)h*NB + b)*NTOK + n)*NTOK + g*16;
#pragma unroll
        for (int q = 0; q < 4; q++) {
            float4 v;
            v.x = vals[q*4+0]*inv; v.y = vals[q*4+1]*inv;
            v.z = vals[q*4+2]*inv; v.w = vals[q*4+3]*inv;
            *(float4*)(wls + n*WLS_LD + g*16 + q*4) = v;
            *(float4*)(wrow + q*4) = v;
        }
        __syncthreads();
    }

    // ---------------- Phase 4: att = w @ v, write x_out ----------------
    {
        const float* wls = smem + WLS_OFF;
        const float* vls = smem + VLS_OFF;
        float aacc[4][2];  // n = ng*4+i, o = cg + 16*j
#pragma unroll
        for (int i = 0; i < 4; i++)
#pragma unroll
            for (int j = 0; j < 2; j++) aacc[i][j] = 0.f;
#pragma unroll
        for (int m4 = 0; m4 < NTOK; m4 += 4) {
            float4 w4[4];
#pragma unroll
            for (int i = 0; i < 4; i++)
                w4[i] = *(const float4*)(wls + (ng*4+i)*WLS_LD + m4);
#pragma unroll
            for (int t = 0; t < 4; t++) {
#pragma unroll
                for (int j = 0; j < 2; j++) {
                    float vv = vls[(m4+t)*KQ_LD + cg + 16*j];
#pragma unroll
                    for (int i = 0; i < 4; i++)
                        aacc[i][j] = fmaf(((const float*)&w4[i])[t], vv, aacc[i][j]);
                }
            }
        }
#pragma unroll
        for (int i = 0; i < 4; i++)
#pragma unroll
            for (int j = 0; j < 2; j++)
                x_out[((size_t)b*NTOK + ng*4+i)*DIM + h*OV + cg + 16*j] = aacc[i][j];
    }
}

__global__ __launch_bounds__(256)
void final_mlp_kernel(const float* __restrict__ x2,   // [NB*NTOK][128]
                      const float* __restrict__ F1w,  // [64][128]
                      const float* __restrict__ F1b,  // [64]
                      const float* __restrict__ F2w,  // [16][64]
                      const float* __restrict__ F2b,  // [16]
                      float* __restrict__ policy)     // [NB*NTOK][16]
{
    __shared__ float xr[4][128];
    __shared__ float hr[4][64];
    const int tid = threadIdx.x;
    const int w = tid >> 6;
    const int l = tid & 63;
    for (int it = 0; it < 16; it++) {
        const int r = blockIdx.x*64 + w*16 + it;
        __syncthreads();   // protect xr/hr from previous iteration readers
        xr[w][l]      = x2[(size_t)r*128 + l];
        xr[w][l + 64] = x2[(size_t)r*128 + 64 + l];
        __syncthreads();
        float acc = F1b[l];
#pragma unroll 8
        for (int f = 0; f < 128; f++) acc = fmaf(xr[w][f], F1w[l*128 + f], acc);
        acc = (acc >= 0.f) ? acc : 0.01f*acc;
        hr[w][l] = acc;
        __syncthreads();
        if (l < 16) {
            float lg = F2b[l];
#pragma unroll 8
            for (int o = 0; o < 64; o++) lg = fmaf(hr[w][o], F2w[l*64 + o], lg);
            float mx = lg;
            mx = fmaxf(mx, __shfl_xor(mx, 1, 16));
            mx = fmaxf(mx, __shfl_xor(mx, 2, 16));
            mx = fmaxf(mx, __shfl_xor(mx, 4, 16));
            mx = fmaxf(mx, __shfl_xor(mx, 8, 16));
            float e = expf(lg - mx);
            float s = e;
            s += __shfl_xor(s, 1, 16);
            s += __shfl_xor(s, 2, 16);
            s += __shfl_xor(s, 4, 16);
            s += __shfl_xor(s, 8, 16);
            policy[(size_t)r*16 + l] = e / s;
        }
    }
}

extern "C" void kernel_launch(void* const* d_in, const int* in_sizes, int n_in,
                              void* d_out, int out_size, void* d_ws, size_t ws_size,
                              hipStream_t stream) {
    const float* states = (const float*)d_in[0];
    const float* E1w = (const float*)d_in[1];  const float* E1b = (const float*)d_in[2];
    const float* K1w = (const float*)d_in[3];  const float* K1b = (const float*)d_in[4];
    const float* Q1w = (const float*)d_in[5];  const float* Q1b = (const float*)d_in[6];
    const float* V1w = (const float*)d_in[7];  const float* V1b = (const float*)d_in[8];
    const float* E2w = (const float*)d_in[9];  const float* E2b = (const float*)d_in[10];
    const float* K2w = (const float*)d_in[11]; const float* K2b = (const float*)d_in[12];
    const float* Q2w = (const float*)d_in[13]; const float* Q2b = (const float*)d_in[14];
    const float* V2w = (const float*)d_in[15]; const float* V2b = (const float*)d_in[16];
    const float* F1w = (const float*)d_in[17]; const float* F1b = (const float*)d_in[18];
    const float* F2w = (const float*)d_in[19]; const float* F2b = (const float*)d_in[20];

    float* out    = (float*)d_out;
    float* policy = out;                        // [512][64][16]
    float* w1     = out + 512*64*16;            // [4][512][64][64]
    float* w2     = w1 + 4*512*64*64;           // [4][512][64][64]

    float* x1 = (float*)d_ws;                   // [512][64][128]
    float* x2 = x1 + 512*64*128;                // [512][64][128]

    attn_stage_kernel<256><<<2048, 256, 0, stream>>>(
        states, E1w, E1b, K1w, K1b, Q1w, Q1b, V1w, V1b, w1, x1);
    attn_stage_kernel<128><<<2048, 256, 0, stream>>>(
        x1, E2w, E2b, K2w, K2b, Q2w, Q2b, V2w, V2b, w2, x2);
    final_mlp_kernel<<<512, 256, 0, stream>>>(x2, F1w, F1b, F2w, F2b, policy);
}

// Round 2
// 371.921 us; speedup vs baseline: 2.7606x; 2.7606x over previous
//
#include <hip/hip_runtime.h>

// ---------------- types / helpers ----------------
typedef __attribute__((ext_vector_type(8))) short short8;   // 8 bf16 = 4 VGPRs (MFMA A/B frag)
typedef __attribute__((ext_vector_type(4))) short short4v;
typedef __attribute__((ext_vector_type(4))) float f32x4;    // MFMA C/D frag

#define MFMA(a, b, c) __builtin_amdgcn_mfma_f32_16x16x32_bf16((a), (b), (c), 0, 0, 0)

__device__ __forceinline__ short f2bf(float f) {   // RNE float->bf16 (bit pattern as short)
    union { float f; unsigned u; } v; v.f = f;
    unsigned r = v.u + 0x7fffu + ((v.u >> 16) & 1u);
    return (short)(r >> 16);
}
__device__ __forceinline__ float bf2f(short s) {
    union { unsigned u; float f; } v; v.u = ((unsigned)(unsigned short)s) << 16; return v.f;
}

// ---------------- weight fp32 -> bf16 conversion (once per launch) ----------------
struct ConvArgs { const float* src[8]; int end[8]; };  // end[] in float4 units, cumulative

__global__ __launch_bounds__(256) void convert_weights_kernel(ConvArgs a, short* __restrict__ dst) {
    int i4 = blockIdx.x * 256 + threadIdx.x;           // exactly 122880 float4s
    int seg = 0;
#pragma unroll
    for (int s = 0; s < 7; s++) seg += (i4 >= a.end[s]) ? 1 : 0;
    int base = (seg == 0) ? 0 : a.end[seg - 1];
    float4 v = ((const float4*)a.src[seg])[i4 - base];
    short4v o; o.x = f2bf(v.x); o.y = f2bf(v.y); o.z = f2bf(v.z); o.w = f2bf(v.w);
    *(short4v*)(dst + (size_t)i4 * 4) = o;             // segments packed contiguously in dst
}

// ---------------- fused attention stage ----------------
// LDS layout (short offsets). Row pads of +8 shorts keep ds_read_b128 16B-aligned
// and make row stride == 4 banks mod 32 -> only free 2-way aliasing.
#define KQ_LD  136
#define VT_LD  72
#define W_LD   72
#define OFF_K  0        // [64][136] overlays X (X dead after se)
#define OFF_Q  8704     // [64][136]
#define OFF_SE 17408    // [64][136]
#define OFF_VT 26112    // [32][72]  v transposed: vT[o][token]
#define OFF_W  8704     // [64][72]  overlays q (q dead after logits)
#define SMEM_SHORTS 28416   // 56,832 B -> 2 blocks/CU

template<int IN, bool XF32>
__global__ __launch_bounds__(256) void attn_stage_kernel(
    const void* __restrict__ xin,                      // [512][64][IN] fp32 (stage1) or bf16 (stage2)
    const short* __restrict__ Ew, const float* __restrict__ Eb,   // Ew bf16 [4][128][IN]
    const short* __restrict__ Kw, const float* __restrict__ Kb,   // [4][128][128]
    const short* __restrict__ Qw, const float* __restrict__ Qb,   // [4][128][128]
    const short* __restrict__ Vw, const float* __restrict__ Vb,   // [4][32][128]
    float* __restrict__ w_out,                          // [4][512][64][64] fp32
    short* __restrict__ x_out)                          // [512][64][128] bf16
{
    __shared__ short sm[SMEM_SHORTS];
    const int tid  = threadIdx.x;
    const int b    = blockIdx.x >> 2;
    const int h    = blockIdx.x & 3;
    const int wv   = tid >> 6;          // wave 0..3
    const int lane = tid & 63;
    const int quad = lane >> 4;         // MFMA k-group / row-group
    const int l16  = lane & 15;         // MFMA m/n index
    const int XLD  = IN + 8;

    // ---- stage X tile into LDS (bf16) ----
    if constexpr (XF32) {
        const float* xb = (const float*)xin + (size_t)b * 64 * IN;
#pragma unroll
        for (int r = 0; r < IN / 16; r++) {             // 64*IN/4 float4s / 256 threads
            int f4 = tid + 256 * r;
            int row = f4 / (IN / 4), c4 = f4 % (IN / 4);
            float4 v = ((const float4*)xb)[f4];
            short4v o; o.x = f2bf(v.x); o.y = f2bf(v.y); o.z = f2bf(v.z); o.w = f2bf(v.w);
            *(short4v*)&sm[row * XLD + c4 * 4] = o;
        }
    } else {
        const short* xb = (const short*)xin + (size_t)b * 64 * IN;
#pragma unroll
        for (int r = 0; r < IN / 32; r++) {             // 64*IN/8 short8s / 256 threads
            int f8 = tid + 256 * r;
            int row = f8 / (IN / 8), c8 = f8 % (IN / 8);
            short8 v = *(const short8*)(xb + (size_t)f8 * 8);
            *(short8*)&sm[row * XLD + c8 * 8] = v;
        }
    }
    __syncthreads();

    // ---- Phase 1: se = leaky(X @ Ew^T + Eb)  [64x128], col-split: wave -> cols wv*32..+31 ----
    {
        const short* ewh = Ew + (size_t)h * 128 * IN;
        f32x4 acc[4][2];
#pragma unroll
        for (int j = 0; j < 2; j++) {
            float bv = Eb[h * 128 + wv * 32 + j * 16 + l16];
            f32x4 c = {bv, bv, bv, bv};
#pragma unroll
            for (int i = 0; i < 4; i++) acc[i][j] = c;
        }
        for (int k0 = 0; k0 < IN; k0 += 32) {
            short8 a[4], bb[2];
#pragma unroll
            for (int i = 0; i < 4; i++)
                a[i] = *(const short8*)&sm[(i * 16 + l16) * XLD + k0 + quad * 8];
#pragma unroll
            for (int j = 0; j < 2; j++)
                bb[j] = *(const short8*)(ewh + (size_t)(wv * 32 + j * 16 + l16) * IN + k0 + quad * 8);
#pragma unroll
            for (int i = 0; i < 4; i++)
#pragma unroll
                for (int j = 0; j < 2; j++)
                    acc[i][j] = MFMA(a[i], bb[j], acc[i][j]);
        }
        // C/D layout: col = n0 + l16, row = m0 + quad*4 + r
#pragma unroll
        for (int i = 0; i < 4; i++)
#pragma unroll
            for (int j = 0; j < 2; j++)
#pragma unroll
                for (int r = 0; r < 4; r++) {
                    float v = acc[i][j][r];
                    v = (v >= 0.f) ? v : 0.01f * v;
                    sm[OFF_SE + (i * 16 + quad * 4 + r) * KQ_LD + wv * 32 + j * 16 + l16] = f2bf(v);
                }
    }
    __syncthreads();   // se published; X now dead (k/q overlay it)

    // ---- Phase 2: k = se@Kw^T+b, q = se@Qw^T+b (fused, shared A-frags); then v ----
    {
        const short* kwh = Kw + (size_t)h * 128 * 128;
        const short* qwh = Qw + (size_t)h * 128 * 128;
        f32x4 kacc[4][2], qacc[4][2];
#pragma unroll
        for (int j = 0; j < 2; j++) {
            float kb = Kb[h * 128 + wv * 32 + j * 16 + l16];
            float qb = Qb[h * 128 + wv * 32 + j * 16 + l16];
            f32x4 kc = {kb, kb, kb, kb}, qc = {qb, qb, qb, qb};
#pragma unroll
            for (int i = 0; i < 4; i++) { kacc[i][j] = kc; qacc[i][j] = qc; }
        }
#pragma unroll
        for (int k0 = 0; k0 < 128; k0 += 32) {
            short8 a[4], kb8[2], qb8[2];
#pragma unroll
            for (int i = 0; i < 4; i++)
                a[i] = *(const short8*)&sm[OFF_SE + (i * 16 + l16) * KQ_LD + k0 + quad * 8];
#pragma unroll
            for (int j = 0; j < 2; j++) {
                kb8[j] = *(const short8*)(kwh + (size_t)(wv * 32 + j * 16 + l16) * 128 + k0 + quad * 8);
                qb8[j] = *(const short8*)(qwh + (size_t)(wv * 32 + j * 16 + l16) * 128 + k0 + quad * 8);
            }
#pragma unroll
            for (int i = 0; i < 4; i++)
#pragma unroll
                for (int j = 0; j < 2; j++) {
                    kacc[i][j] = MFMA(a[i], kb8[j], kacc[i][j]);
                    qacc[i][j] = MFMA(a[i], qb8[j], qacc[i][j]);
                }
        }
#pragma unroll
        for (int i = 0; i < 4; i++)
#pragma unroll
            for (int j = 0; j < 2; j++)
#pragma unroll
                for (int r = 0; r < 4; r++) {
                    int row = i * 16 + quad * 4 + r, col = wv * 32 + j * 16 + l16;
                    sm[OFF_K + row * KQ_LD + col] = f2bf(kacc[i][j][r]);
                    sm[OFF_Q + row * KQ_LD + col] = f2bf(qacc[i][j][r]);
                }
        // v = leaky(se @ Vw^T + Vb) [64x32]; wave -> rows (wv&1)*32..+31, cols (wv>>1)*16..+15
        const short* vwh = Vw + (size_t)h * 32 * 128;
        const int n0v = (wv >> 1) * 16, mrow = (wv & 1) * 32;
        float vb = Vb[h * 32 + n0v + l16];
        f32x4 vacc[2]; vacc[0] = (f32x4){vb, vb, vb, vb}; vacc[1] = vacc[0];
#pragma unroll
        for (int k0 = 0; k0 < 128; k0 += 32) {
            short8 a0 = *(const short8*)&sm[OFF_SE + (mrow + l16) * KQ_LD + k0 + quad * 8];
            short8 a1 = *(const short8*)&sm[OFF_SE + (mrow + 16 + l16) * KQ_LD + k0 + quad * 8];
            short8 b8 = *(const short8*)(vwh + (size_t)(n0v + l16) * 128 + k0 + quad * 8);
            vacc[0] = MFMA(a0, b8, vacc[0]);
            vacc[1] = MFMA(a1, b8, vacc[1]);
        }
        // store transposed: vT[o][token] so PV B-frag is contiguous 16B
#pragma unroll
        for (int i = 0; i < 2; i++)
#pragma unroll
            for (int r = 0; r < 4; r++) {
                float v = vacc[i][r];
                v = (v >= 0.f) ? v : 0.01f * v;
                sm[OFF_VT + (n0v + l16) * VT_LD + mrow + i * 16 + quad * 4 + r] = f2bf(v);
            }
    }
    __syncthreads();

    // ---- Phase 3: logits = q @ k^T (row-split: wave -> rows wv*16..+15), softmax ----
    f32x4 lacc[4];
#pragma unroll
    for (int jj = 0; jj < 4; jj++) lacc[jj] = (f32x4){0.f, 0.f, 0.f, 0.f};
#pragma unroll
    for (int k0 = 0; k0 < 128; k0 += 32) {
        short8 a = *(const short8*)&sm[OFF_Q + (wv * 16 + l16) * KQ_LD + k0 + quad * 8];
#pragma unroll
        for (int jj = 0; jj < 4; jj++) {
            short8 b8 = *(const short8*)&sm[OFF_K + (jj * 16 + l16) * KQ_LD + k0 + quad * 8];
            lacc[jj] = MFMA(a, b8, lacc[jj]);
        }
    }
    __syncthreads();   // all q reads done before w overlays q

    {
        const float scale = 0.08838834764831845f;   // 1/sqrt(128)
        float mx[4], inv[4];
#pragma unroll
        for (int r = 0; r < 4; r++) {
            float m = lacc[0][r];
#pragma unroll
            for (int jj = 1; jj < 4; jj++) m = fmaxf(m, lacc[jj][r]);
#pragma unroll
            for (int s = 1; s < 16; s <<= 1) m = fmaxf(m, __shfl_xor(m, s, 16));
            mx[r] = m;
        }
        float sum[4] = {0.f, 0.f, 0.f, 0.f};
#pragma unroll
        for (int jj = 0; jj < 4; jj++)
#pragma unroll
            for (int r = 0; r < 4; r++) {
                float e = __expf((lacc[jj][r] - mx[r]) * scale);
                lacc[jj][r] = e; sum[r] += e;
            }
#pragma unroll
        for (int r = 0; r < 4; r++) {
#pragma unroll
            for (int s = 1; s < 16; s <<= 1) sum[r] += __shfl_xor(sum[r], s, 16);
            inv[r] = 1.0f / sum[r];
        }
        float* wbase = w_out + ((size_t)(h * 512 + b)) * 64 * 64;
#pragma unroll
        for (int r = 0; r < 4; r++) {
            int row = wv * 16 + quad * 4 + r;
#pragma unroll
            for (int jj = 0; jj < 4; jj++) {
                float wval = lacc[jj][r] * inv[r];
                wbase[(size_t)row * 64 + jj * 16 + l16] = wval;
                sm[OFF_W + row * W_LD + jj * 16 + l16] = f2bf(wval);
            }
        }
    }
    __syncthreads();

    // ---- Phase 4: att = w @ v -> x_out (bf16). wave -> rows wv*16..+15, cols 0..31 ----
    {
        f32x4 aacc[2]; aacc[0] = (f32x4){0.f, 0.f, 0.f, 0.f}; aacc[1] = aacc[0];
#pragma unroll
        for (int k0 = 0; k0 < 64; k0 += 32) {
            short8 a = *(const short8*)&sm[OFF_W + (wv * 16 + l16) * W_LD + k0 + quad * 8];
#pragma unroll
            for (int j = 0; j < 2; j++) {
                short8 b8 = *(const short8*)&sm[OFF_VT + (j * 16 + l16) * VT_LD + k0 + quad * 8];
                aacc[j] = MFMA(a, b8, aacc[j]);
            }
        }
        short* xob = x_out + (size_t)b * 64 * 128;
#pragma unroll
        for (int j = 0; j < 2; j++)
#pragma unroll
            for (int r = 0; r < 4; r++)
                xob[(size_t)(wv * 16 + quad * 4 + r) * 128 + h * 32 + j * 16 + l16] = f2bf(aacc[j][r]);
    }
}

// ---------------- final MLP + softmax (x2 now bf16) ----------------
__global__ __launch_bounds__(256)
void final_mlp_kernel(const short* __restrict__ x2,   // [NB*NTOK][128] bf16
                      const float* __restrict__ F1w,  // [64][128]
                      const float* __restrict__ F1b,  // [64]
                      const float* __restrict__ F2w,  // [16][64]
                      const float* __restrict__ F2b,  // [16]
                      float* __restrict__ policy)     // [NB*NTOK][16]
{
    __shared__ float xr[4][128];
    __shared__ float hr[4][64];
    const int tid = threadIdx.x;
    const int w = tid >> 6;
    const int l = tid & 63;
    for (int it = 0; it < 16; it++) {
        const int r = blockIdx.x * 64 + w * 16 + it;
        __syncthreads();
        xr[w][l]      = bf2f(x2[(size_t)r * 128 + l]);
        xr[w][l + 64] = bf2f(x2[(size_t)r * 128 + 64 + l]);
        __syncthreads();
        float acc = F1b[l];
#pragma unroll 8
        for (int f = 0; f < 128; f++) acc = fmaf(xr[w][f], F1w[l * 128 + f], acc);
        acc = (acc >= 0.f) ? acc : 0.01f * acc;
        hr[w][l] = acc;
        __syncthreads();
        if (l < 16) {
            float lg = F2b[l];
#pragma unroll 8
            for (int o = 0; o < 64; o++) lg = fmaf(hr[w][o], F2w[l * 64 + o], lg);
            float mx = lg;
            mx = fmaxf(mx, __shfl_xor(mx, 1, 16));
            mx = fmaxf(mx, __shfl_xor(mx, 2, 16));
            mx = fmaxf(mx, __shfl_xor(mx, 4, 16));
            mx = fmaxf(mx, __shfl_xor(mx, 8, 16));
            float e = __expf(lg - mx);
            float s = e;
            s += __shfl_xor(s, 1, 16);
            s += __shfl_xor(s, 2, 16);
            s += __shfl_xor(s, 4, 16);
            s += __shfl_xor(s, 8, 16);
            policy[(size_t)r * 16 + l] = e / s;
        }
    }
}

// ---------------- launcher ----------------
extern "C" void kernel_launch(void* const* d_in, const int* in_sizes, int n_in,
                              void* d_out, int out_size, void* d_ws, size_t ws_size,
                              hipStream_t stream) {
    const float* states = (const float*)d_in[0];
    const float* E1w = (const float*)d_in[1];  const float* E1b = (const float*)d_in[2];
    const float* K1w = (const float*)d_in[3];  const float* K1b = (const float*)d_in[4];
    const float* Q1w = (const float*)d_in[5];  const float* Q1b = (const float*)d_in[6];
    const float* V1w = (const float*)d_in[7];  const float* V1b = (const float*)d_in[8];
    const float* E2w = (const float*)d_in[9];  const float* E2b = (const float*)d_in[10];
    const float* K2w = (const float*)d_in[11]; const float* K2b = (const float*)d_in[12];
    const float* Q2w = (const float*)d_in[13]; const float* Q2b = (const float*)d_in[14];
    const float* V2w = (const float*)d_in[15]; const float* V2b = (const float*)d_in[16];
    const float* F1w = (const float*)d_in[17]; const float* F1b = (const float*)d_in[18];
    const float* F2w = (const float*)d_in[19]; const float* F2b = (const float*)d_in[20];

    float* out    = (float*)d_out;
    float* policy = out;                        // [512][64][16]
    float* w1     = out + 512 * 64 * 16;        // [4][512][64][64]
    float* w2     = w1 + 4 * 512 * 64 * 64;     // [4][512][64][64]

    // ws layout (shorts): x1b [4.19M] | x2b [4.19M] | bf16 weights [491,520]
    short* wsb = (short*)d_ws;
    short* x1b = wsb;
    short* x2b = wsb + 4194304;
    short* wts = wsb + 8388608;
    short* wE1 = wts;            short* wK1 = wts + 131072;
    short* wQ1 = wts + 196608;   short* wV1 = wts + 262144;
    short* wE2 = wts + 278528;   short* wK2 = wts + 344064;
    short* wQ2 = wts + 409600;   short* wV2 = wts + 475136;

    ConvArgs ca;
    ca.src[0] = E1w; ca.src[1] = K1w; ca.src[2] = Q1w; ca.src[3] = V1w;
    ca.src[4] = E2w; ca.src[5] = K2w; ca.src[6] = Q2w; ca.src[7] = V2w;
    ca.end[0] = 32768;  ca.end[1] = 49152;  ca.end[2] = 65536;  ca.end[3] = 69632;
    ca.end[4] = 86016;  ca.end[5] = 102400; ca.end[6] = 118784; ca.end[7] = 122880;
    convert_weights_kernel<<<480, 256, 0, stream>>>(ca, wts);

    attn_stage_kernel<256, true><<<2048, 256, 0, stream>>>(
        (const void*)states, wE1, E1b, wK1, K1b, wQ1, Q1b, wV1, V1b, w1, x1b);
    attn_stage_kernel<128, false><<<2048, 256, 0, stream>>>(
        (const void*)x1b, wE2, E2b, wK2, K2b, wQ2, Q2b, wV2, V2b, w2, x2b);
    final_mlp_kernel<<<512, 256, 0, stream>>>(x2b, F1w, F1b, F2w, F2b, policy);
}

// Round 3
// 232.639 us; speedup vs baseline: 4.4135x; 1.5987x over previous
//
#include <hip/hip_runtime.h>

// ---------------- types / helpers ----------------
typedef __attribute__((ext_vector_type(8))) short short8;   // 8 bf16 = 4 VGPRs (MFMA A/B frag)
typedef __attribute__((ext_vector_type(4))) short short4v;
typedef __attribute__((ext_vector_type(4))) float f32x4;    // MFMA C/D frag

#define MFMA(a, b, c) __builtin_amdgcn_mfma_f32_16x16x32_bf16((a), (b), (c), 0, 0, 0)

__device__ __forceinline__ short f2bf(float f) {   // RNE float->bf16 (bit pattern as short)
    union { float f; unsigned u; } v; v.f = f;
    unsigned r = v.u + 0x7fffu + ((v.u >> 16) & 1u);
    return (short)(r >> 16);
}
__device__ __forceinline__ float bf2f(short s) {
    union { unsigned u; float f; } v; v.u = ((unsigned)(unsigned short)s) << 16; return v.f;
}

// ---------------- weight fp32 -> bf16 conversion (once per launch) ----------------
struct ConvArgs { const float* src[10]; int end[10]; };  // end[] in float4 units, cumulative

__global__ __launch_bounds__(256) void convert_weights_kernel(ConvArgs a, short* __restrict__ dst) {
    int i4 = blockIdx.x * 256 + threadIdx.x;           // exactly 125184 float4s
    int seg = 0;
#pragma unroll
    for (int s = 0; s < 9; s++) seg += (i4 >= a.end[s]) ? 1 : 0;
    int base = (seg == 0) ? 0 : a.end[seg - 1];
    float4 v = ((const float4*)a.src[seg])[i4 - base];
    short4v o; o.x = f2bf(v.x); o.y = f2bf(v.y); o.z = f2bf(v.z); o.w = f2bf(v.w);
    *(short4v*)(dst + (size_t)i4 * 4) = o;             // segments packed contiguously in dst
}

// ---------------- fused attention stage ----------------
// LDS layout (short offsets). Row pads of +8 shorts keep ds_read_b128 16B-aligned
// and make row stride == 4 banks mod 32 -> only free 2-way aliasing.
#define KQ_LD  136
#define VT_LD  72
#define W_LD   72
#define OFF_K  0        // [64][136] overlays X (X dead after se)
#define OFF_Q  8704     // [64][136]
#define OFF_SE 17408    // [64][136]
#define OFF_VT 26112    // [32][72]  v transposed: vT[o][token]
#define OFF_W  8704     // [64][72]  overlays q (q dead after logits)
#define SMEM_SHORTS 28416   // 56,832 B -> 2 blocks/CU

template<int IN, bool XF32>
__global__ __launch_bounds__(256) void attn_stage_kernel(
    const void* __restrict__ xin,                      // [512][64][IN] fp32 (stage1) or bf16 (stage2)
    const short* __restrict__ Ew, const float* __restrict__ Eb,   // Ew bf16 [4][128][IN]
    const short* __restrict__ Kw, const float* __restrict__ Kb,   // [4][128][128]
    const short* __restrict__ Qw, const float* __restrict__ Qb,   // [4][128][128]
    const short* __restrict__ Vw, const float* __restrict__ Vb,   // [4][32][128]
    float* __restrict__ w_out,                          // [4][512][64][64] fp32
    short* __restrict__ x_out)                          // [512][64][128] bf16
{
    __shared__ short sm[SMEM_SHORTS];
    const int tid  = threadIdx.x;
    const int b    = blockIdx.x >> 2;
    const int h    = blockIdx.x & 3;
    const int wv   = tid >> 6;          // wave 0..3
    const int lane = tid & 63;
    const int quad = lane >> 4;         // MFMA k-group / row-group
    const int l16  = lane & 15;         // MFMA m/n index
    const int XLD  = IN + 8;

    // ---- stage X tile into LDS (bf16) ----
    if constexpr (XF32) {
        const float* xb = (const float*)xin + (size_t)b * 64 * IN;
#pragma unroll
        for (int r = 0; r < IN / 16; r++) {             // 64*IN/4 float4s / 256 threads
            int f4 = tid + 256 * r;
            int row = f4 / (IN / 4), c4 = f4 % (IN / 4);
            float4 v = ((const float4*)xb)[f4];
            short4v o; o.x = f2bf(v.x); o.y = f2bf(v.y); o.z = f2bf(v.z); o.w = f2bf(v.w);
            *(short4v*)&sm[row * XLD + c4 * 4] = o;
        }
    } else {
        const short* xb = (const short*)xin + (size_t)b * 64 * IN;
#pragma unroll
        for (int r = 0; r < IN / 32; r++) {             // 64*IN/8 short8s / 256 threads
            int f8 = tid + 256 * r;
            int row = f8 / (IN / 8), c8 = f8 % (IN / 8);
            short8 v = *(const short8*)(xb + (size_t)f8 * 8);
            *(short8*)&sm[row * XLD + c8 * 8] = v;
        }
    }
    __syncthreads();

    // ---- Phase 1: se = leaky(X @ Ew^T + Eb)  [64x128], col-split: wave -> cols wv*32..+31 ----
    {
        const short* ewh = Ew + (size_t)h * 128 * IN;
        f32x4 acc[4][2];
#pragma unroll
        for (int j = 0; j < 2; j++) {
            float bv = Eb[h * 128 + wv * 32 + j * 16 + l16];
            f32x4 c = {bv, bv, bv, bv};
#pragma unroll
            for (int i = 0; i < 4; i++) acc[i][j] = c;
        }
        for (int k0 = 0; k0 < IN; k0 += 32) {
            short8 a[4], bb[2];
#pragma unroll
            for (int i = 0; i < 4; i++)
                a[i] = *(const short8*)&sm[(i * 16 + l16) * XLD + k0 + quad * 8];
#pragma unroll
            for (int j = 0; j < 2; j++)
                bb[j] = *(const short8*)(ewh + (size_t)(wv * 32 + j * 16 + l16) * IN + k0 + quad * 8);
#pragma unroll
            for (int i = 0; i < 4; i++)
#pragma unroll
                for (int j = 0; j < 2; j++)
                    acc[i][j] = MFMA(a[i], bb[j], acc[i][j]);
        }
        // C/D layout: col = n0 + l16, row = m0 + quad*4 + r
#pragma unroll
        for (int i = 0; i < 4; i++)
#pragma unroll
            for (int j = 0; j < 2; j++)
#pragma unroll
                for (int r = 0; r < 4; r++) {
                    float v = acc[i][j][r];
                    v = (v >= 0.f) ? v : 0.01f * v;
                    sm[OFF_SE + (i * 16 + quad * 4 + r) * KQ_LD + wv * 32 + j * 16 + l16] = f2bf(v);
                }
    }
    __syncthreads();   // se published; X now dead (k/q overlay it)

    // ---- Phase 2: k = se@Kw^T+b, q = se@Qw^T+b (fused, shared A-frags); then v ----
    {
        const short* kwh = Kw + (size_t)h * 128 * 128;
        const short* qwh = Qw + (size_t)h * 128 * 128;
        f32x4 kacc[4][2], qacc[4][2];
#pragma unroll
        for (int j = 0; j < 2; j++) {
            float kb = Kb[h * 128 + wv * 32 + j * 16 + l16];
            float qb = Qb[h * 128 + wv * 32 + j * 16 + l16];
            f32x4 kc = {kb, kb, kb, kb}, qc = {qb, qb, qb, qb};
#pragma unroll
            for (int i = 0; i < 4; i++) { kacc[i][j] = kc; qacc[i][j] = qc; }
        }
#pragma unroll
        for (int k0 = 0; k0 < 128; k0 += 32) {
            short8 a[4], kb8[2], qb8[2];
#pragma unroll
            for (int i = 0; i < 4; i++)
                a[i] = *(const short8*)&sm[OFF_SE + (i * 16 + l16) * KQ_LD + k0 + quad * 8];
#pragma unroll
            for (int j = 0; j < 2; j++) {
                kb8[j] = *(const short8*)(kwh + (size_t)(wv * 32 + j * 16 + l16) * 128 + k0 + quad * 8);
                qb8[j] = *(const short8*)(qwh + (size_t)(wv * 32 + j * 16 + l16) * 128 + k0 + quad * 8);
            }
#pragma unroll
            for (int i = 0; i < 4; i++)
#pragma unroll
                for (int j = 0; j < 2; j++) {
                    kacc[i][j] = MFMA(a[i], kb8[j], kacc[i][j]);
                    qacc[i][j] = MFMA(a[i], qb8[j], qacc[i][j]);
                }
        }
#pragma unroll
        for (int i = 0; i < 4; i++)
#pragma unroll
            for (int j = 0; j < 2; j++)
#pragma unroll
                for (int r = 0; r < 4; r++) {
                    int row = i * 16 + quad * 4 + r, col = wv * 32 + j * 16 + l16;
                    sm[OFF_K + row * KQ_LD + col] = f2bf(kacc[i][j][r]);
                    sm[OFF_Q + row * KQ_LD + col] = f2bf(qacc[i][j][r]);
                }
        // v = leaky(se @ Vw^T + Vb) [64x32]; wave -> rows (wv&1)*32..+31, cols (wv>>1)*16..+15
        const short* vwh = Vw + (size_t)h * 32 * 128;
        const int n0v = (wv >> 1) * 16, mrow = (wv & 1) * 32;
        float vb = Vb[h * 32 + n0v + l16];
        f32x4 vacc[2]; vacc[0] = (f32x4){vb, vb, vb, vb}; vacc[1] = vacc[0];
#pragma unroll
        for (int k0 = 0; k0 < 128; k0 += 32) {
            short8 a0 = *(const short8*)&sm[OFF_SE + (mrow + l16) * KQ_LD + k0 + quad * 8];
            short8 a1 = *(const short8*)&sm[OFF_SE + (mrow + 16 + l16) * KQ_LD + k0 + quad * 8];
            short8 b8 = *(const short8*)(vwh + (size_t)(n0v + l16) * 128 + k0 + quad * 8);
            vacc[0] = MFMA(a0, b8, vacc[0]);
            vacc[1] = MFMA(a1, b8, vacc[1]);
        }
        // store transposed: vT[o][token] so PV B-frag is contiguous 16B
#pragma unroll
        for (int i = 0; i < 2; i++)
#pragma unroll
            for (int r = 0; r < 4; r++) {
                float v = vacc[i][r];
                v = (v >= 0.f) ? v : 0.01f * v;
                sm[OFF_VT + (n0v + l16) * VT_LD + mrow + i * 16 + quad * 4 + r] = f2bf(v);
            }
    }
    __syncthreads();

    // ---- Phase 3: logits = q @ k^T (row-split: wave -> rows wv*16..+15), softmax ----
    f32x4 lacc[4];
#pragma unroll
    for (int jj = 0; jj < 4; jj++) lacc[jj] = (f32x4){0.f, 0.f, 0.f, 0.f};
#pragma unroll
    for (int k0 = 0; k0 < 128; k0 += 32) {
        short8 a = *(const short8*)&sm[OFF_Q + (wv * 16 + l16) * KQ_LD + k0 + quad * 8];
#pragma unroll
        for (int jj = 0; jj < 4; jj++) {
            short8 b8 = *(const short8*)&sm[OFF_K + (jj * 16 + l16) * KQ_LD + k0 + quad * 8];
            lacc[jj] = MFMA(a, b8, lacc[jj]);
        }
    }
    __syncthreads();   // all q reads done before w overlays q

    {
        const float scale = 0.08838834764831845f;   // 1/sqrt(128)
        float mx[4], inv[4];
#pragma unroll
        for (int r = 0; r < 4; r++) {
            float m = lacc[0][r];
#pragma unroll
            for (int jj = 1; jj < 4; jj++) m = fmaxf(m, lacc[jj][r]);
#pragma unroll
            for (int s = 1; s < 16; s <<= 1) m = fmaxf(m, __shfl_xor(m, s, 16));
            mx[r] = m;
        }
        float sum[4] = {0.f, 0.f, 0.f, 0.f};
#pragma unroll
        for (int jj = 0; jj < 4; jj++)
#pragma unroll
            for (int r = 0; r < 4; r++) {
                float e = __expf((lacc[jj][r] - mx[r]) * scale);
                lacc[jj][r] = e; sum[r] += e;
            }
#pragma unroll
        for (int r = 0; r < 4; r++) {
#pragma unroll
            for (int s = 1; s < 16; s <<= 1) sum[r] += __shfl_xor(sum[r], s, 16);
            inv[r] = 1.0f / sum[r];
        }
        float* wbase = w_out + ((size_t)(h * 512 + b)) * 64 * 64;
#pragma unroll
        for (int r = 0; r < 4; r++) {
            int row = wv * 16 + quad * 4 + r;
#pragma unroll
            for (int jj = 0; jj < 4; jj++) {
                float wval = lacc[jj][r] * inv[r];
                wbase[(size_t)row * 64 + jj * 16 + l16] = wval;
                sm[OFF_W + row * W_LD + jj * 16 + l16] = f2bf(wval);
            }
        }
    }
    __syncthreads();

    // ---- Phase 4: att = w @ v -> x_out (bf16). wave -> rows wv*16..+15, cols 0..31 ----
    {
        f32x4 aacc[2]; aacc[0] = (f32x4){0.f, 0.f, 0.f, 0.f}; aacc[1] = aacc[0];
#pragma unroll
        for (int k0 = 0; k0 < 64; k0 += 32) {
            short8 a = *(const short8*)&sm[OFF_W + (wv * 16 + l16) * W_LD + k0 + quad * 8];
#pragma unroll
            for (int j = 0; j < 2; j++) {
                short8 b8 = *(const short8*)&sm[OFF_VT + (j * 16 + l16) * VT_LD + k0 + quad * 8];
                aacc[j] = MFMA(a, b8, aacc[j]);
            }
        }
        short* xob = x_out + (size_t)b * 64 * 128;
#pragma unroll
        for (int j = 0; j < 2; j++)
#pragma unroll
            for (int r = 0; r < 4; r++)
                xob[(size_t)(wv * 16 + quad * 4 + r) * 128 + h * 32 + j * 16 + l16] = f2bf(aacc[j][r]);
    }
}

// ---------------- final MLP + softmax, MFMA version ----------------
// Grid 512 x 256. Each wave owns 16 rows end-to-end; one barrier total.
#define H_LD 72
__global__ __launch_bounds__(256)
void final_mlp_mfma_kernel(const short* __restrict__ x2,    // [32768][128] bf16
                           const short* __restrict__ F1wb,  // [64][128] bf16
                           const float* __restrict__ F1b,   // [64]
                           const short* __restrict__ F2wb,  // [16][64] bf16
                           const float* __restrict__ F2b,   // [16]
                           float* __restrict__ policy)      // [32768][16]
{
    __shared__ short hsm[4][16 * H_LD];   // per-wave h tile [16 rows][64 cols]
    const int tid  = threadIdx.x;
    const int wv   = tid >> 6;
    const int lane = tid & 63;
    const int quad = lane >> 4;
    const int l16  = lane & 15;
    const int rowbase = blockIdx.x * 64 + wv * 16;

    // ---- F1: h = leaky(x2[rows] @ F1w^T + F1b), rows = rowbase..+15 ----
    short8 a[4];
    const short* xrow = x2 + (size_t)(rowbase + l16) * 128;
#pragma unroll
    for (int k = 0; k < 4; k++) a[k] = *(const short8*)(xrow + k * 32 + quad * 8);
    f32x4 acc[4];
#pragma unroll
    for (int j = 0; j < 4; j++) { float bv = F1b[j * 16 + l16]; acc[j] = (f32x4){bv, bv, bv, bv}; }
#pragma unroll
    for (int k = 0; k < 4; k++)
#pragma unroll
        for (int j = 0; j < 4; j++) {
            short8 b8 = *(const short8*)(F1wb + (size_t)(j * 16 + l16) * 128 + k * 32 + quad * 8);
            acc[j] = MFMA(a[k], b8, acc[j]);
        }
    // leaky + stage h in LDS (C-layout -> A-layout transpose)
    short* hh = &hsm[wv][0];
#pragma unroll
    for (int j = 0; j < 4; j++)
#pragma unroll
        for (int r = 0; r < 4; r++) {
            float v = acc[j][r];
            v = (v >= 0.f) ? v : 0.01f * v;
            hh[(quad * 4 + r) * H_LD + j * 16 + l16] = f2bf(v);
        }
    __syncthreads();

    // ---- F2: logits = h @ F2w^T + F2b  [16 rows x 16 p], K=64 ----
    f32x4 lg;
    { float bv = F2b[l16]; lg = (f32x4){bv, bv, bv, bv}; }
#pragma unroll
    for (int k = 0; k < 2; k++) {
        short8 a2 = *(const short8*)(hh + l16 * H_LD + k * 32 + quad * 8);
        short8 b8 = *(const short8*)(F2wb + (size_t)l16 * 64 + k * 32 + quad * 8);
        lg = MFMA(a2, b8, lg);
    }
    // softmax over p (= l16 across the 16 lanes of this quad), per row r
#pragma unroll
    for (int r = 0; r < 4; r++) {
        float m = lg[r];
        m = fmaxf(m, __shfl_xor(m, 1, 16));
        m = fmaxf(m, __shfl_xor(m, 2, 16));
        m = fmaxf(m, __shfl_xor(m, 4, 16));
        m = fmaxf(m, __shfl_xor(m, 8, 16));
        float e = __expf(lg[r] - m);
        float s = e;
        s += __shfl_xor(s, 1, 16);
        s += __shfl_xor(s, 2, 16);
        s += __shfl_xor(s, 4, 16);
        s += __shfl_xor(s, 8, 16);
        policy[(size_t)(rowbase + quad * 4 + r) * 16 + l16] = e / s;
    }
}

// ---------------- launcher ----------------
extern "C" void kernel_launch(void* const* d_in, const int* in_sizes, int n_in,
                              void* d_out, int out_size, void* d_ws, size_t ws_size,
                              hipStream_t stream) {
    const float* states = (const float*)d_in[0];
    const float* E1w = (const float*)d_in[1];  const float* E1b = (const float*)d_in[2];
    const float* K1w = (const float*)d_in[3];  const float* K1b = (const float*)d_in[4];
    const float* Q1w = (const float*)d_in[5];  const float* Q1b = (const float*)d_in[6];
    const float* V1w = (const float*)d_in[7];  const float* V1b = (const float*)d_in[8];
    const float* E2w = (const float*)d_in[9];  const float* E2b = (const float*)d_in[10];
    const float* K2w = (const float*)d_in[11]; const float* K2b = (const float*)d_in[12];
    const float* Q2w = (const float*)d_in[13]; const float* Q2b = (const float*)d_in[14];
    const float* V2w = (const float*)d_in[15]; const float* V2b = (const float*)d_in[16];
    const float* F1w = (const float*)d_in[17]; const float* F1b = (const float*)d_in[18];
    const float* F2w = (const float*)d_in[19]; const float* F2b = (const float*)d_in[20];

    float* out    = (float*)d_out;
    float* policy = out;                        // [512][64][16]
    float* w1     = out + 512 * 64 * 16;        // [4][512][64][64]
    float* w2     = w1 + 4 * 512 * 64 * 64;     // [4][512][64][64]

    // ws layout (shorts): x1b | x2b | bf16 weights
    short* wsb = (short*)d_ws;
    short* x1b = wsb;
    short* x2b = wsb + 4194304;
    short* wts = wsb + 8388608;
    short* wE1 = wts;            short* wK1 = wts + 131072;
    short* wQ1 = wts + 196608;   short* wV1 = wts + 262144;
    short* wE2 = wts + 278528;   short* wK2 = wts + 344064;
    short* wQ2 = wts + 409600;   short* wV2 = wts + 475136;
    short* wF1 = wts + 491520;   short* wF2 = wts + 499712;

    ConvArgs ca;
    ca.src[0] = E1w; ca.src[1] = K1w; ca.src[2] = Q1w; ca.src[3] = V1w;
    ca.src[4] = E2w; ca.src[5] = K2w; ca.src[6] = Q2w; ca.src[7] = V2w;
    ca.src[8] = F1w; ca.src[9] = F2w;
    ca.end[0] = 32768;  ca.end[1] = 49152;  ca.end[2] = 65536;  ca.end[3] = 69632;
    ca.end[4] = 86016;  ca.end[5] = 102400; ca.end[6] = 118784; ca.end[7] = 122880;
    ca.end[8] = 124928; ca.end[9] = 125184;
    convert_weights_kernel<<<489, 256, 0, stream>>>(ca, wts);

    attn_stage_kernel<256, true><<<2048, 256, 0, stream>>>(
        (const void*)states, wE1, E1b, wK1, K1b, wQ1, Q1b, wV1, V1b, w1, x1b);
    attn_stage_kernel<128, false><<<2048, 256, 0, stream>>>(
        (const void*)x1b, wE2, E2b, wK2, K2b, wQ2, Q2b, wV2, V2b, w2, x2b);
    final_mlp_mfma_kernel<<<512, 256, 0, stream>>>(x2b, wF1, F1b, wF2, F2b, policy);
}

// Round 4
// 220.382 us; speedup vs baseline: 4.6589x; 1.0556x over previous
//
#include <hip/hip_runtime.h>

// ---------------- types / helpers ----------------
typedef __attribute__((ext_vector_type(8))) short short8;   // 8 bf16 = 4 VGPRs (MFMA A/B frag)
typedef __attribute__((ext_vector_type(4))) short short4v;
typedef __attribute__((ext_vector_type(4))) float f32x4;    // MFMA C/D frag

#define MFMA(a, b, c) __builtin_amdgcn_mfma_f32_16x16x32_bf16((a), (b), (c), 0, 0, 0)

__device__ __forceinline__ short f2bf(float f) {   // RNE float->bf16 (bit pattern as short)
    union { float f; unsigned u; } v; v.f = f;
    unsigned r = v.u + 0x7fffu + ((v.u >> 16) & 1u);
    return (short)(r >> 16);
}
__device__ __forceinline__ float bf2f(short s) {
    union { unsigned u; float f; } v; v.u = ((unsigned)(unsigned short)s) << 16; return v.f;
}

// ---------------- weight fp32 -> bf16 conversion (once per launch) ----------------
struct ConvArgs { const float* src[10]; int end[10]; };  // end[] in float4 units, cumulative

__global__ __launch_bounds__(256) void convert_weights_kernel(ConvArgs a, short* __restrict__ dst) {
    int i4 = blockIdx.x * 256 + threadIdx.x;           // exactly 125184 float4s
    int seg = 0;
#pragma unroll
    for (int s = 0; s < 9; s++) seg += (i4 >= a.end[s]) ? 1 : 0;
    int base = (seg == 0) ? 0 : a.end[seg - 1];
    float4 v = ((const float4*)a.src[seg])[i4 - base];
    short4v o; o.x = f2bf(v.x); o.y = f2bf(v.y); o.z = f2bf(v.z); o.w = f2bf(v.w);
    *(short4v*)(dst + (size_t)i4 * 4) = o;             // segments packed contiguously in dst
}

// ---------------- fused attention stage ----------------
// LDS layout (short offsets). Row pads of +8 shorts keep ds_read_b128 16B-aligned
// and make row stride == 4 banks mod 32 -> only free 2-way aliasing.
// 52,224 B total -> 3 blocks/CU (the round-4 occupancy lever).
#define KQ_LD  136
#define VT_LD  72
#define W_LD   72
#define OFF_K  0        // [64][136] overlays X (X dead after phase 1)
#define OFF_Q  8704     // [64][136]
#define OFF_SE 17408    // [64][136]
#define OFF_VT 17408    // [32][72]  v transposed, written OVER SE after phase-2 barrier
#define OFF_W  8704     // [64][72]  overlays q (q dead after logits)
#define SMEM_SHORTS 26112   // 52,224 B

template<int IN, bool XF32>
__global__ __launch_bounds__(256, 3) void attn_stage_kernel(
    const void* __restrict__ xin,                      // [512][64][IN] fp32 (stage1) or bf16 (stage2)
    const short* __restrict__ Ew, const float* __restrict__ Eb,   // Ew bf16 [4][128][IN]
    const short* __restrict__ Kw, const float* __restrict__ Kb,   // [4][128][128]
    const short* __restrict__ Qw, const float* __restrict__ Qb,   // [4][128][128]
    const short* __restrict__ Vw, const float* __restrict__ Vb,   // [4][32][128]
    float* __restrict__ w_out,                          // [4][512][64][64] fp32
    short* __restrict__ x_out)                          // [512][64][128] bf16
{
    __shared__ short sm[SMEM_SHORTS];
    const int tid  = threadIdx.x;
    const int b    = blockIdx.x >> 2;
    const int h    = blockIdx.x & 3;
    const int wv   = tid >> 6;          // wave 0..3
    const int lane = tid & 63;
    const int quad = lane >> 4;         // MFMA k-group / row-group
    const int l16  = lane & 15;         // MFMA m/n index
    const int XLD  = IN + 8;
    constexpr int NK1 = IN / 32;        // phase-1 k-steps (8 or 4)

    // ---- stage X tile into LDS (bf16) ----
    if constexpr (XF32) {
        const float* xb = (const float*)xin + (size_t)b * 64 * IN;
#pragma unroll
        for (int r = 0; r < IN / 16; r++) {             // 64*IN/4 float4s / 256 threads
            int f4 = tid + 256 * r;
            int row = f4 / (IN / 4), c4 = f4 % (IN / 4);
            float4 v = ((const float4*)xb)[f4];
            short4v o; o.x = f2bf(v.x); o.y = f2bf(v.y); o.z = f2bf(v.z); o.w = f2bf(v.w);
            *(short4v*)&sm[row * XLD + c4 * 4] = o;
        }
    } else {
        const short* xb = (const short*)xin + (size_t)b * 64 * IN;
#pragma unroll
        for (int r = 0; r < IN / 32; r++) {             // 64*IN/8 short8s / 256 threads
            int f8 = tid + 256 * r;
            int row = f8 / (IN / 8), c8 = f8 % (IN / 8);
            short8 v = *(const short8*)(xb + (size_t)f8 * 8);
            *(short8*)&sm[row * XLD + c8 * 8] = v;
        }
    }

    // ---- prefetch ALL phase-1 B-frags (weights) while X staging settles ----
    short8 ebf[NK1 * 2];
    {
        const short* ewh = Ew + (size_t)h * 128 * IN;
#pragma unroll
        for (int k0i = 0; k0i < NK1; k0i++)
#pragma unroll
            for (int j = 0; j < 2; j++)
                ebf[k0i * 2 + j] = *(const short8*)(ewh + (size_t)(wv * 32 + j * 16 + l16) * IN + k0i * 32 + quad * 8);
    }
    __syncthreads();

    // ---- Phase 1: se = leaky(X @ Ew^T + Eb)  [64x128], col-split: wave -> cols wv*32..+31 ----
    {
        f32x4 acc[4][2];
#pragma unroll
        for (int j = 0; j < 2; j++) {
            float bv = Eb[h * 128 + wv * 32 + j * 16 + l16];
            f32x4 c = {bv, bv, bv, bv};
#pragma unroll
            for (int i = 0; i < 4; i++) acc[i][j] = c;
        }
#pragma unroll
        for (int k0i = 0; k0i < NK1; k0i++) {
            short8 a[4];
#pragma unroll
            for (int i = 0; i < 4; i++)
                a[i] = *(const short8*)&sm[(i * 16 + l16) * XLD + k0i * 32 + quad * 8];
#pragma unroll
            for (int i = 0; i < 4; i++)
#pragma unroll
                for (int j = 0; j < 2; j++)
                    acc[i][j] = MFMA(a[i], ebf[k0i * 2 + j], acc[i][j]);
        }
        // C/D layout: col = n0 + l16, row = m0 + quad*4 + r
#pragma unroll
        for (int i = 0; i < 4; i++)
#pragma unroll
            for (int j = 0; j < 2; j++)
#pragma unroll
                for (int r = 0; r < 4; r++) {
                    float v = acc[i][j][r];
                    v = (v >= 0.f) ? v : 0.01f * v;
                    sm[OFF_SE + (i * 16 + quad * 4 + r) * KQ_LD + wv * 32 + j * 16 + l16] = f2bf(v);
                }
    }
    __syncthreads();   // se published; X now dead (k/q overlay it)

    // ---- Phase 2: k = se@Kw^T+b, q = se@Qw^T+b (fused, shared A-frags); then v ----
    f32x4 vacc[2];     // v accumulators survive across the barrier; VT written after it
    {
        // prefetch all K/Q B-frags: 16 x 16B in flight behind one wait
        short8 kbf[8], qbf[8];
        const short* kwh = Kw + (size_t)h * 128 * 128;
        const short* qwh = Qw + (size_t)h * 128 * 128;
#pragma unroll
        for (int k0i = 0; k0i < 4; k0i++)
#pragma unroll
            for (int j = 0; j < 2; j++) {
                kbf[k0i * 2 + j] = *(const short8*)(kwh + (size_t)(wv * 32 + j * 16 + l16) * 128 + k0i * 32 + quad * 8);
                qbf[k0i * 2 + j] = *(const short8*)(qwh + (size_t)(wv * 32 + j * 16 + l16) * 128 + k0i * 32 + quad * 8);
            }
        f32x4 kacc[4][2], qacc[4][2];
#pragma unroll
        for (int j = 0; j < 2; j++) {
            float kb = Kb[h * 128 + wv * 32 + j * 16 + l16];
            float qb = Qb[h * 128 + wv * 32 + j * 16 + l16];
            f32x4 kc = {kb, kb, kb, kb}, qc = {qb, qb, qb, qb};
#pragma unroll
            for (int i = 0; i < 4; i++) { kacc[i][j] = kc; qacc[i][j] = qc; }
        }
#pragma unroll
        for (int k0i = 0; k0i < 4; k0i++) {
            short8 a[4];
#pragma unroll
            for (int i = 0; i < 4; i++)
                a[i] = *(const short8*)&sm[OFF_SE + (i * 16 + l16) * KQ_LD + k0i * 32 + quad * 8];
#pragma unroll
            for (int i = 0; i < 4; i++)
#pragma unroll
                for (int j = 0; j < 2; j++) {
                    kacc[i][j] = MFMA(a[i], kbf[k0i * 2 + j], kacc[i][j]);
                    qacc[i][j] = MFMA(a[i], qbf[k0i * 2 + j], qacc[i][j]);
                }
        }
#pragma unroll
        for (int i = 0; i < 4; i++)
#pragma unroll
            for (int j = 0; j < 2; j++)
#pragma unroll
                for (int r = 0; r < 4; r++) {
                    int row = i * 16 + quad * 4 + r, col = wv * 32 + j * 16 + l16;
                    sm[OFF_K + row * KQ_LD + col] = f2bf(kacc[i][j][r]);
                    sm[OFF_Q + row * KQ_LD + col] = f2bf(qacc[i][j][r]);
                }
        // v = leaky(se @ Vw^T + Vb) [64x32]; wave -> rows (wv&1)*32..+31, cols (wv>>1)*16..+15
        const short* vwh = Vw + (size_t)h * 32 * 128;
        const int n0v = (wv >> 1) * 16, mrow = (wv & 1) * 32;
        short8 vbf[4];
#pragma unroll
        for (int k0i = 0; k0i < 4; k0i++)
            vbf[k0i] = *(const short8*)(vwh + (size_t)(n0v + l16) * 128 + k0i * 32 + quad * 8);
        float vb = Vb[h * 32 + n0v + l16];
        vacc[0] = (f32x4){vb, vb, vb, vb}; vacc[1] = vacc[0];
#pragma unroll
        for (int k0i = 0; k0i < 4; k0i++) {
            short8 a0 = *(const short8*)&sm[OFF_SE + (mrow + l16) * KQ_LD + k0i * 32 + quad * 8];
            short8 a1 = *(const short8*)&sm[OFF_SE + (mrow + 16 + l16) * KQ_LD + k0i * 32 + quad * 8];
            vacc[0] = MFMA(a0, vbf[k0i], vacc[0]);
            vacc[1] = MFMA(a1, vbf[k0i], vacc[1]);
        }
    }
    __syncthreads();   // k,q published; ALL waves done reading SE -> SE region reusable

    // ---- write vT over SE region (leaky applied); then logits MFMAs ----
    {
        const int n0v = (wv >> 1) * 16, mrow = (wv & 1) * 32;
#pragma unroll
        for (int i = 0; i < 2; i++)
#pragma unroll
            for (int r = 0; r < 4; r++) {
                float v = vacc[i][r];
                v = (v >= 0.f) ? v : 0.01f * v;
                sm[OFF_VT + (n0v + l16) * VT_LD + mrow + i * 16 + quad * 4 + r] = f2bf(v);
            }
    }

    // ---- Phase 3: logits = q @ k^T (row-split: wave -> rows wv*16..+15), softmax ----
    f32x4 lacc[4];
#pragma unroll
    for (int jj = 0; jj < 4; jj++) lacc[jj] = (f32x4){0.f, 0.f, 0.f, 0.f};
#pragma unroll
    for (int k0 = 0; k0 < 128; k0 += 32) {
        short8 a = *(const short8*)&sm[OFF_Q + (wv * 16 + l16) * KQ_LD + k0 + quad * 8];
#pragma unroll
        for (int jj = 0; jj < 4; jj++) {
            short8 b8 = *(const short8*)&sm[OFF_K + (jj * 16 + l16) * KQ_LD + k0 + quad * 8];
            lacc[jj] = MFMA(a, b8, lacc[jj]);
        }
    }
    __syncthreads();   // q reads done (W overlays q); VT fully written for phase 4

    {
        const float scale = 0.08838834764831845f;   // 1/sqrt(128)
        float mx[4], inv[4];
#pragma unroll
        for (int r = 0; r < 4; r++) {
            float m = lacc[0][r];
#pragma unroll
            for (int jj = 1; jj < 4; jj++) m = fmaxf(m, lacc[jj][r]);
#pragma unroll
            for (int s = 1; s < 16; s <<= 1) m = fmaxf(m, __shfl_xor(m, s, 16));
            mx[r] = m;
        }
        float sum[4] = {0.f, 0.f, 0.f, 0.f};
#pragma unroll
        for (int jj = 0; jj < 4; jj++)
#pragma unroll
            for (int r = 0; r < 4; r++) {
                float e = __expf((lacc[jj][r] - mx[r]) * scale);
                lacc[jj][r] = e; sum[r] += e;
            }
#pragma unroll
        for (int r = 0; r < 4; r++) {
#pragma unroll
            for (int s = 1; s < 16; s <<= 1) sum[r] += __shfl_xor(sum[r], s, 16);
            inv[r] = 1.0f / sum[r];
        }
        float* wbase = w_out + ((size_t)(h * 512 + b)) * 64 * 64;
#pragma unroll
        for (int r = 0; r < 4; r++) {
            int row = wv * 16 + quad * 4 + r;
#pragma unroll
            for (int jj = 0; jj < 4; jj++) {
                float wval = lacc[jj][r] * inv[r];
                wbase[(size_t)row * 64 + jj * 16 + l16] = wval;
                sm[OFF_W + row * W_LD + jj * 16 + l16] = f2bf(wval);
            }
        }
    }
    __syncthreads();

    // ---- Phase 4: att = w @ v -> x_out (bf16). wave -> rows wv*16..+15, cols 0..31 ----
    {
        f32x4 aacc[2]; aacc[0] = (f32x4){0.f, 0.f, 0.f, 0.f}; aacc[1] = aacc[0];
#pragma unroll
        for (int k0 = 0; k0 < 64; k0 += 32) {
            short8 a = *(const short8*)&sm[OFF_W + (wv * 16 + l16) * W_LD + k0 + quad * 8];
#pragma unroll
            for (int j = 0; j < 2; j++) {
                short8 b8 = *(const short8*)&sm[OFF_VT + (j * 16 + l16) * VT_LD + k0 + quad * 8];
                aacc[j] = MFMA(a, b8, aacc[j]);
            }
        }
        short* xob = x_out + (size_t)b * 64 * 128;
#pragma unroll
        for (int j = 0; j < 2; j++)
#pragma unroll
            for (int r = 0; r < 4; r++)
                xob[(size_t)(wv * 16 + quad * 4 + r) * 128 + h * 32 + j * 16 + l16] = f2bf(aacc[j][r]);
    }
}

// ---------------- final MLP + softmax, MFMA version ----------------
// Grid 512 x 256. Each wave owns 16 rows end-to-end; one barrier total.
#define H_LD 72
__global__ __launch_bounds__(256)
void final_mlp_mfma_kernel(const short* __restrict__ x2,    // [32768][128] bf16
                           const short* __restrict__ F1wb,  // [64][128] bf16
                           const float* __restrict__ F1b,   // [64]
                           const short* __restrict__ F2wb,  // [16][64] bf16
                           const float* __restrict__ F2b,   // [16]
                           float* __restrict__ policy)      // [32768][16]
{
    __shared__ short hsm[4][16 * H_LD];   // per-wave h tile [16 rows][64 cols]
    const int tid  = threadIdx.x;
    const int wv   = tid >> 6;
    const int lane = tid & 63;
    const int quad = lane >> 4;
    const int l16  = lane & 15;
    const int rowbase = blockIdx.x * 64 + wv * 16;

    // ---- F1: h = leaky(x2[rows] @ F1w^T + F1b), rows = rowbase..+15 ----
    short8 a[4];
    const short* xrow = x2 + (size_t)(rowbase + l16) * 128;
#pragma unroll
    for (int k = 0; k < 4; k++) a[k] = *(const short8*)(xrow + k * 32 + quad * 8);
    f32x4 acc[4];
#pragma unroll
    for (int j = 0; j < 4; j++) { float bv = F1b[j * 16 + l16]; acc[j] = (f32x4){bv, bv, bv, bv}; }
#pragma unroll
    for (int k = 0; k < 4; k++)
#pragma unroll
        for (int j = 0; j < 4; j++) {
            short8 b8 = *(const short8*)(F1wb + (size_t)(j * 16 + l16) * 128 + k * 32 + quad * 8);
            acc[j] = MFMA(a[k], b8, acc[j]);
        }
    // leaky + stage h in LDS (C-layout -> A-layout transpose)
    short* hh = &hsm[wv][0];
#pragma unroll
    for (int j = 0; j < 4; j++)
#pragma unroll
        for (int r = 0; r < 4; r++) {
            float v = acc[j][r];
            v = (v >= 0.f) ? v : 0.01f * v;
            hh[(quad * 4 + r) * H_LD + j * 16 + l16] = f2bf(v);
        }
    __syncthreads();

    // ---- F2: logits = h @ F2w^T + F2b  [16 rows x 16 p], K=64 ----
    f32x4 lg;
    { float bv = F2b[l16]; lg = (f32x4){bv, bv, bv, bv}; }
#pragma unroll
    for (int k = 0; k < 2; k++) {
        short8 a2 = *(const short8*)(hh + l16 * H_LD + k * 32 + quad * 8);
        short8 b8 = *(const short8*)(F2wb + (size_t)l16 * 64 + k * 32 + quad * 8);
        lg = MFMA(a2, b8, lg);
    }
    // softmax over p (= l16 across the 16 lanes of this quad), per row r
#pragma unroll
    for (int r = 0; r < 4; r++) {
        float m = lg[r];
        m = fmaxf(m, __shfl_xor(m, 1, 16));
        m = fmaxf(m, __shfl_xor(m, 2, 16));
        m = fmaxf(m, __shfl_xor(m, 4, 16));
        m = fmaxf(m, __shfl_xor(m, 8, 16));
        float e = __expf(lg[r] - m);
        float s = e;
        s += __shfl_xor(s, 1, 16);
        s += __shfl_xor(s, 2, 16);
        s += __shfl_xor(s, 4, 16);
        s += __shfl_xor(s, 8, 16);
        policy[(size_t)(rowbase + quad * 4 + r) * 16 + l16] = e / s;
    }
}

// ---------------- launcher ----------------
extern "C" void kernel_launch(void* const* d_in, const int* in_sizes, int n_in,
                              void* d_out, int out_size, void* d_ws, size_t ws_size,
                              hipStream_t stream) {
    const float* states = (const float*)d_in[0];
    const float* E1w = (const float*)d_in[1];  const float* E1b = (const float*)d_in[2];
    const float* K1w = (const float*)d_in[3];  const float* K1b = (const float*)d_in[4];
    const float* Q1w = (const float*)d_in[5];  const float* Q1b = (const float*)d_in[6];
    const float* V1w = (const float*)d_in[7];  const float* V1b = (const float*)d_in[8];
    const float* E2w = (const float*)d_in[9];  const float* E2b = (const float*)d_in[10];
    const float* K2w = (const float*)d_in[11]; const float* K2b = (const float*)d_in[12];
    const float* Q2w = (const float*)d_in[13]; const float* Q2b = (const float*)d_in[14];
    const float* V2w = (const float*)d_in[15]; const float* V2b = (const float*)d_in[16];
    const float* F1w = (const float*)d_in[17]; const float* F1b = (const float*)d_in[18];
    const float* F2w = (const float*)d_in[19]; const float* F2b = (const float*)d_in[20];

    float* out    = (float*)d_out;
    float* policy = out;                        // [512][64][16]
    float* w1     = out + 512 * 64 * 16;        // [4][512][64][64]
    float* w2     = w1 + 4 * 512 * 64 * 64;     // [4][512][64][64]

    // ws layout (shorts): x1b | x2b | bf16 weights
    short* wsb = (short*)d_ws;
    short* x1b = wsb;
    short* x2b = wsb + 4194304;
    short* wts = wsb + 8388608;
    short* wE1 = wts;            short* wK1 = wts + 131072;
    short* wQ1 = wts + 196608;   short* wV1 = wts + 262144;
    short* wE2 = wts + 278528;   short* wK2 = wts + 344064;
    short* wQ2 = wts + 409600;   short* wV2 = wts + 475136;
    short* wF1 = wts + 491520;   short* wF2 = wts + 499712;

    ConvArgs ca;
    ca.src[0] = E1w; ca.src[1] = K1w; ca.src[2] = Q1w; ca.src[3] = V1w;
    ca.src[4] = E2w; ca.src[5] = K2w; ca.src[6] = Q2w; ca.src[7] = V2w;
    ca.src[8] = F1w; ca.src[9] = F2w;
    ca.end[0] = 32768;  ca.end[1] = 49152;  ca.end[2] = 65536;  ca.end[3] = 69632;
    ca.end[4] = 86016;  ca.end[5] = 102400; ca.end[6] = 118784; ca.end[7] = 122880;
    ca.end[8] = 124928; ca.end[9] = 125184;
    convert_weights_kernel<<<489, 256, 0, stream>>>(ca, wts);

    attn_stage_kernel<256, true><<<2048, 256, 0, stream>>>(
        (const void*)states, wE1, E1b, wK1, K1b, wQ1, Q1b, wV1, V1b, w1, x1b);
    attn_stage_kernel<128, false><<<2048, 256, 0, stream>>>(
        (const void*)x1b, wE2, E2b, wK2, K2b, wQ2, Q2b, wV2, V2b, w2, x2b);
    final_mlp_mfma_kernel<<<512, 256, 0, stream>>>(x2b, wF1, F1b, wF2, F2b, policy);
}

// Round 5
// 219.259 us; speedup vs baseline: 4.6828x; 1.0051x over previous
//
#include <hip/hip_runtime.h>

// ---------------- types / helpers ----------------
typedef __attribute__((ext_vector_type(8))) short short8;   // 8 bf16 = 4 VGPRs (MFMA A/B frag)
typedef __attribute__((ext_vector_type(4))) short short4v;
typedef __attribute__((ext_vector_type(4))) float f32x4;    // MFMA C/D frag

#define MFMA(a, b, c) __builtin_amdgcn_mfma_f32_16x16x32_bf16((a), (b), (c), 0, 0, 0)

__device__ __forceinline__ short f2bf(float f) {   // RNE float->bf16 (bit pattern as short)
    union { float f; unsigned u; } v; v.f = f;
    unsigned r = v.u + 0x7fffu + ((v.u >> 16) & 1u);
    return (short)(r >> 16);
}
__device__ __forceinline__ float bf2f(short s) {
    union { unsigned u; float f; } v; v.u = ((unsigned)(unsigned short)s) << 16; return v.f;
}

// ---------------- weight fp32 -> bf16 conversion (once per launch) ----------------
struct ConvArgs { const float* src[10]; int end[10]; };  // end[] in float4 units, cumulative

__global__ __launch_bounds__(256) void convert_weights_kernel(ConvArgs a, short* __restrict__ dst) {
    int i4 = blockIdx.x * 256 + threadIdx.x;           // exactly 125184 float4s
    int seg = 0;
#pragma unroll
    for (int s = 0; s < 9; s++) seg += (i4 >= a.end[s]) ? 1 : 0;
    int base = (seg == 0) ? 0 : a.end[seg - 1];
    float4 v = ((const float4*)a.src[seg])[i4 - base];
    short4v o; o.x = f2bf(v.x); o.y = f2bf(v.y); o.z = f2bf(v.z); o.w = f2bf(v.w);
    *(short4v*)(dst + (size_t)i4 * 4) = o;             // segments packed contiguously in dst
}

// ---------------- fused attention stage ----------------
// LDS layout (short offsets). Row pads of +8 shorts keep ds_read_b128 16B-aligned
// and make bank aliasing uniform (free 2-way only).
// 52,224 B total -> 3 blocks/CU.
#define KQ_LD  136
#define VT_LD  72
#define W_LD   72
#define OFF_K  0        // [64][136] overlays X (X dead after phase 1); fp32 W overlays K after logits
#define OFF_Q  8704     // [64][136]
#define OFF_SE 17408    // [64][136]
#define OFF_VT 17408    // [32][72]  v transposed, written OVER SE after phase-2 barrier
#define OFF_W  8704     // [64][72]  bf16 w overlays q (q dead after logits)
#define W32_LD 68       // fp32 w staging: [64][68] floats == 17,408 B == K region exactly
#define SMEM_SHORTS 26112   // 52,224 B

template<int IN, bool XF32>
__global__ __launch_bounds__(256, 3) void attn_stage_kernel(
    const void* __restrict__ xin,                      // [512][64][IN] fp32 (stage1) or bf16 (stage2)
    const short* __restrict__ Ew, const float* __restrict__ Eb,   // Ew bf16 [4][128][IN]
    const short* __restrict__ Kw, const float* __restrict__ Kb,   // [4][128][128]
    const short* __restrict__ Qw, const float* __restrict__ Qb,   // [4][128][128]
    const short* __restrict__ Vw, const float* __restrict__ Vb,   // [4][32][128]
    float* __restrict__ w_out,                          // [4][512][64][64] fp32
    short* __restrict__ x_out)                          // [512][64][128] bf16
{
    __shared__ short sm[SMEM_SHORTS];
    const int tid  = threadIdx.x;
    // XCD-affinity decode: the 4 h-blocks of one b share blockIdx%8 -> same XCD L2,
    // so states[b]/x1b[b] are fetched once per b instead of 4x.
    const int b    = blockIdx.x & 511;
    const int h    = blockIdx.x >> 9;
    const int wv   = tid >> 6;          // wave 0..3
    const int lane = tid & 63;
    const int quad = lane >> 4;         // MFMA k-group / row-group
    const int l16  = lane & 15;         // MFMA m/n index
    const int XLD  = IN + 8;
    constexpr int NK1 = IN / 32;        // phase-1 k-steps (8 or 4)

    // ---- stage X tile into LDS (bf16) ----
    if constexpr (XF32) {
        const float* xb = (const float*)xin + (size_t)b * 64 * IN;
#pragma unroll
        for (int r = 0; r < IN / 16; r++) {             // 64*IN/4 float4s / 256 threads
            int f4 = tid + 256 * r;
            int row = f4 / (IN / 4), c4 = f4 % (IN / 4);
            float4 v = ((const float4*)xb)[f4];
            short4v o; o.x = f2bf(v.x); o.y = f2bf(v.y); o.z = f2bf(v.z); o.w = f2bf(v.w);
            *(short4v*)&sm[row * XLD + c4 * 4] = o;
        }
    } else {
        const short* xb = (const short*)xin + (size_t)b * 64 * IN;
#pragma unroll
        for (int r = 0; r < IN / 32; r++) {             // 64*IN/8 short8s / 256 threads
            int f8 = tid + 256 * r;
            int row = f8 / (IN / 8), c8 = f8 % (IN / 8);
            short8 v = *(const short8*)(xb + (size_t)f8 * 8);
            *(short8*)&sm[row * XLD + c8 * 8] = v;
        }
    }

    // ---- prefetch ALL phase-1 B-frags (weights) while X staging settles ----
    short8 ebf[NK1 * 2];
    {
        const short* ewh = Ew + (size_t)h * 128 * IN;
#pragma unroll
        for (int k0i = 0; k0i < NK1; k0i++)
#pragma unroll
            for (int j = 0; j < 2; j++)
                ebf[k0i * 2 + j] = *(const short8*)(ewh + (size_t)(wv * 32 + j * 16 + l16) * IN + k0i * 32 + quad * 8);
    }
    __syncthreads();

    short8 kbf[8];   // K-weight frags, prefetched during phase-1 epilogue

    // ---- Phase 1: se = leaky(X @ Ew^T + Eb)  [64x128], col-split: wave -> cols wv*32..+31 ----
    {
        f32x4 acc[4][2];
#pragma unroll
        for (int j = 0; j < 2; j++) {
            float bv = Eb[h * 128 + wv * 32 + j * 16 + l16];
            f32x4 c = {bv, bv, bv, bv};
#pragma unroll
            for (int i = 0; i < 4; i++) acc[i][j] = c;
        }
#pragma unroll
        for (int k0i = 0; k0i < NK1; k0i++) {
            short8 a[4];
#pragma unroll
            for (int i = 0; i < 4; i++)
                a[i] = *(const short8*)&sm[(i * 16 + l16) * XLD + k0i * 32 + quad * 8];
#pragma unroll
            for (int i = 0; i < 4; i++)
#pragma unroll
                for (int j = 0; j < 2; j++)
                    acc[i][j] = MFMA(a[i], ebf[k0i * 2 + j], acc[i][j]);
        }
        // hoisted prefetch: Kw frags fly during phase-1 epilogue + barrier (ebf now dead)
        {
            const short* kwh = Kw + (size_t)h * 128 * 128;
#pragma unroll
            for (int k0i = 0; k0i < 4; k0i++)
#pragma unroll
                for (int j = 0; j < 2; j++)
                    kbf[k0i * 2 + j] = *(const short8*)(kwh + (size_t)(wv * 32 + j * 16 + l16) * 128 + k0i * 32 + quad * 8);
        }
        // C/D layout: col = n0 + l16, row = m0 + quad*4 + r
#pragma unroll
        for (int i = 0; i < 4; i++)
#pragma unroll
            for (int j = 0; j < 2; j++)
#pragma unroll
                for (int r = 0; r < 4; r++) {
                    float v = acc[i][j][r];
                    v = (v >= 0.f) ? v : 0.01f * v;
                    sm[OFF_SE + (i * 16 + quad * 4 + r) * KQ_LD + wv * 32 + j * 16 + l16] = f2bf(v);
                }
    }
    __syncthreads();   // se published; X now dead (k/q overlay it)

    // ---- Phase 2: k = se@Kw^T+b, q = se@Qw^T+b (fused, shared A-frags); then v ----
    f32x4 vacc[2];     // v accumulators survive across the barrier; VT written after it
    {
        // prefetch Q B-frags (K frags already in kbf)
        short8 qbf[8];
        const short* qwh = Qw + (size_t)h * 128 * 128;
#pragma unroll
        for (int k0i = 0; k0i < 4; k0i++)
#pragma unroll
            for (int j = 0; j < 2; j++)
                qbf[k0i * 2 + j] = *(const short8*)(qwh + (size_t)(wv * 32 + j * 16 + l16) * 128 + k0i * 32 + quad * 8);
        f32x4 kacc[4][2], qacc[4][2];
#pragma unroll
        for (int j = 0; j < 2; j++) {
            float kb = Kb[h * 128 + wv * 32 + j * 16 + l16];
            float qb = Qb[h * 128 + wv * 32 + j * 16 + l16];
            f32x4 kc = {kb, kb, kb, kb}, qc = {qb, qb, qb, qb};
#pragma unroll
            for (int i = 0; i < 4; i++) { kacc[i][j] = kc; qacc[i][j] = qc; }
        }
#pragma unroll
        for (int k0i = 0; k0i < 4; k0i++) {
            short8 a[4];
#pragma unroll
            for (int i = 0; i < 4; i++)
                a[i] = *(const short8*)&sm[OFF_SE + (i * 16 + l16) * KQ_LD + k0i * 32 + quad * 8];
#pragma unroll
            for (int i = 0; i < 4; i++)
#pragma unroll
                for (int j = 0; j < 2; j++) {
                    kacc[i][j] = MFMA(a[i], kbf[k0i * 2 + j], kacc[i][j]);
                    qacc[i][j] = MFMA(a[i], qbf[k0i * 2 + j], qacc[i][j]);
                }
        }
#pragma unroll
        for (int i = 0; i < 4; i++)
#pragma unroll
            for (int j = 0; j < 2; j++)
#pragma unroll
                for (int r = 0; r < 4; r++) {
                    int row = i * 16 + quad * 4 + r, col = wv * 32 + j * 16 + l16;
                    sm[OFF_K + row * KQ_LD + col] = f2bf(kacc[i][j][r]);
                    sm[OFF_Q + row * KQ_LD + col] = f2bf(qacc[i][j][r]);
                }
        // v = leaky(se @ Vw^T + Vb) [64x32]; wave -> rows (wv&1)*32..+31, cols (wv>>1)*16..+15
        const short* vwh = Vw + (size_t)h * 32 * 128;
        const int n0v = (wv >> 1) * 16, mrow = (wv & 1) * 32;
        short8 vbf[4];
#pragma unroll
        for (int k0i = 0; k0i < 4; k0i++)
            vbf[k0i] = *(const short8*)(vwh + (size_t)(n0v + l16) * 128 + k0i * 32 + quad * 8);
        float vb = Vb[h * 32 + n0v + l16];
        vacc[0] = (f32x4){vb, vb, vb, vb}; vacc[1] = vacc[0];
#pragma unroll
        for (int k0i = 0; k0i < 4; k0i++) {
            short8 a0 = *(const short8*)&sm[OFF_SE + (mrow + l16) * KQ_LD + k0i * 32 + quad * 8];
            short8 a1 = *(const short8*)&sm[OFF_SE + (mrow + 16 + l16) * KQ_LD + k0i * 32 + quad * 8];
            vacc[0] = MFMA(a0, vbf[k0i], vacc[0]);
            vacc[1] = MFMA(a1, vbf[k0i], vacc[1]);
        }
    }
    __syncthreads();   // k,q published; ALL waves done reading SE -> SE region reusable

    // ---- write vT over SE region (leaky applied); then logits MFMAs ----
    {
        const int n0v = (wv >> 1) * 16, mrow = (wv & 1) * 32;
#pragma unroll
        for (int i = 0; i < 2; i++)
#pragma unroll
            for (int r = 0; r < 4; r++) {
                float v = vacc[i][r];
                v = (v >= 0.f) ? v : 0.01f * v;
                sm[OFF_VT + (n0v + l16) * VT_LD + mrow + i * 16 + quad * 4 + r] = f2bf(v);
            }
    }

    // ---- Phase 3: logits = q @ k^T (row-split: wave -> rows wv*16..+15), softmax ----
    f32x4 lacc[4];
#pragma unroll
    for (int jj = 0; jj < 4; jj++) lacc[jj] = (f32x4){0.f, 0.f, 0.f, 0.f};
#pragma unroll
    for (int k0 = 0; k0 < 128; k0 += 32) {
        short8 a = *(const short8*)&sm[OFF_Q + (wv * 16 + l16) * KQ_LD + k0 + quad * 8];
#pragma unroll
        for (int jj = 0; jj < 4; jj++) {
            short8 b8 = *(const short8*)&sm[OFF_K + (jj * 16 + l16) * KQ_LD + k0 + quad * 8];
            lacc[jj] = MFMA(a, b8, lacc[jj]);
        }
    }
    __syncthreads();   // q,k reads done: W (bf16) overlays q, W32 (fp32) overlays k

    {
        const float scale = 0.08838834764831845f;   // 1/sqrt(128)
        float* w32 = (float*)sm;                    // [64][68] fp32 over K region
        float mx[4], inv[4];
#pragma unroll
        for (int r = 0; r < 4; r++) {
            float m = lacc[0][r];
#pragma unroll
            for (int jj = 1; jj < 4; jj++) m = fmaxf(m, lacc[jj][r]);
#pragma unroll
            for (int s = 1; s < 16; s <<= 1) m = fmaxf(m, __shfl_xor(m, s, 16));
            mx[r] = m;
        }
        float sum[4] = {0.f, 0.f, 0.f, 0.f};
#pragma unroll
        for (int jj = 0; jj < 4; jj++)
#pragma unroll
            for (int r = 0; r < 4; r++) {
                float e = __expf((lacc[jj][r] - mx[r]) * scale);
                lacc[jj][r] = e; sum[r] += e;
            }
#pragma unroll
        for (int r = 0; r < 4; r++) {
#pragma unroll
            for (int s = 1; s < 16; s <<= 1) sum[r] += __shfl_xor(sum[r], s, 16);
            inv[r] = 1.0f / sum[r];
        }
#pragma unroll
        for (int r = 0; r < 4; r++) {
            int row = wv * 16 + quad * 4 + r;
#pragma unroll
            for (int jj = 0; jj < 4; jj++) {
                float wval = lacc[jj][r] * inv[r];
                w32[row * W32_LD + jj * 16 + l16] = wval;
                sm[OFF_W + row * W_LD + jj * 16 + l16] = f2bf(wval);
            }
        }
    }
    __syncthreads();

    // ---- stream w_out from LDS: full-line coalesced float4 nontemporal stores (no RFO) ----
    {
        const float* w32 = (const float*)sm;
        float* wbase = w_out + ((size_t)(h * 512 + b)) * 64 * 64;
#pragma unroll
        for (int s = 0; s < 4; s++) {
            int idx = tid + 256 * s;               // float4 index 0..1023 over [64][64]
            int row = idx >> 4, c4 = (idx & 15) * 4;
            f32x4 v = *(const f32x4*)&w32[row * W32_LD + c4];
            __builtin_nontemporal_store(v, (f32x4*)(wbase + idx * 4));
        }
    }

    // ---- Phase 4: att = w @ v -> x_out (bf16). wave -> rows wv*16..+15, cols 0..31 ----
    {
        f32x4 aacc[2]; aacc[0] = (f32x4){0.f, 0.f, 0.f, 0.f}; aacc[1] = aacc[0];
#pragma unroll
        for (int k0 = 0; k0 < 64; k0 += 32) {
            short8 a = *(const short8*)&sm[OFF_W + (wv * 16 + l16) * W_LD + k0 + quad * 8];
#pragma unroll
            for (int j = 0; j < 2; j++) {
                short8 b8 = *(const short8*)&sm[OFF_VT + (j * 16 + l16) * VT_LD + k0 + quad * 8];
                aacc[j] = MFMA(a, b8, aacc[j]);
            }
        }
        short* xob = x_out + (size_t)b * 64 * 128;
#pragma unroll
        for (int j = 0; j < 2; j++)
#pragma unroll
            for (int r = 0; r < 4; r++)
                xob[(size_t)(wv * 16 + quad * 4 + r) * 128 + h * 32 + j * 16 + l16] = f2bf(aacc[j][r]);
    }
}

// ---------------- final MLP + softmax, MFMA version ----------------
// Grid 512 x 256. Each wave owns 16 rows end-to-end; one barrier total.
#define H_LD 72
__global__ __launch_bounds__(256)
void final_mlp_mfma_kernel(const short* __restrict__ x2,    // [32768][128] bf16
                           const short* __restrict__ F1wb,  // [64][128] bf16
                           const float* __restrict__ F1b,   // [64]
                           const short* __restrict__ F2wb,  // [16][64] bf16
                           const float* __restrict__ F2b,   // [16]
                           float* __restrict__ policy)      // [32768][16]
{
    __shared__ short hsm[4][16 * H_LD];   // per-wave h tile [16 rows][64 cols]
    const int tid  = threadIdx.x;
    const int wv   = tid >> 6;
    const int lane = tid & 63;
    const int quad = lane >> 4;
    const int l16  = lane & 15;
    const int rowbase = blockIdx.x * 64 + wv * 16;

    // ---- F1: h = leaky(x2[rows] @ F1w^T + F1b), rows = rowbase..+15 ----
    short8 a[4];
    const short* xrow = x2 + (size_t)(rowbase + l16) * 128;
#pragma unroll
    for (int k = 0; k < 4; k++) a[k] = *(const short8*)(xrow + k * 32 + quad * 8);
    f32x4 acc[4];
#pragma unroll
    for (int j = 0; j < 4; j++) { float bv = F1b[j * 16 + l16]; acc[j] = (f32x4){bv, bv, bv, bv}; }
#pragma unroll
    for (int k = 0; k < 4; k++)
#pragma unroll
        for (int j = 0; j < 4; j++) {
            short8 b8 = *(const short8*)(F1wb + (size_t)(j * 16 + l16) * 128 + k * 32 + quad * 8);
            acc[j] = MFMA(a[k], b8, acc[j]);
        }
    // leaky + stage h in LDS (C-layout -> A-layout transpose)
    short* hh = &hsm[wv][0];
#pragma unroll
    for (int j = 0; j < 4; j++)
#pragma unroll
        for (int r = 0; r < 4; r++) {
            float v = acc[j][r];
            v = (v >= 0.f) ? v : 0.01f * v;
            hh[(quad * 4 + r) * H_LD + j * 16 + l16] = f2bf(v);
        }
    __syncthreads();

    // ---- F2: logits = h @ F2w^T + F2b  [16 rows x 16 p], K=64 ----
    f32x4 lg;
    { float bv = F2b[l16]; lg = (f32x4){bv, bv, bv, bv}; }
#pragma unroll
    for (int k = 0; k < 2; k++) {
        short8 a2 = *(const short8*)(hh + l16 * H_LD + k * 32 + quad * 8);
        short8 b8 = *(const short8*)(F2wb + (size_t)l16 * 64 + k * 32 + quad * 8);
        lg = MFMA(a2, b8, lg);
    }
    // softmax over p (= l16 across the 16 lanes of this quad), per row r
#pragma unroll
    for (int r = 0; r < 4; r++) {
        float m = lg[r];
        m = fmaxf(m, __shfl_xor(m, 1, 16));
        m = fmaxf(m, __shfl_xor(m, 2, 16));
        m = fmaxf(m, __shfl_xor(m, 4, 16));
        m = fmaxf(m, __shfl_xor(m, 8, 16));
        float e = __expf(lg[r] - m);
        float s = e;
        s += __shfl_xor(s, 1, 16);
        s += __shfl_xor(s, 2, 16);
        s += __shfl_xor(s, 4, 16);
        s += __shfl_xor(s, 8, 16);
        policy[(size_t)(rowbase + quad * 4 + r) * 16 + l16] = e / s;
    }
}

// ---------------- launcher ----------------
extern "C" void kernel_launch(void* const* d_in, const int* in_sizes, int n_in,
                              void* d_out, int out_size, void* d_ws, size_t ws_size,
                              hipStream_t stream) {
    const float* states = (const float*)d_in[0];
    const float* E1w = (const float*)d_in[1];  const float* E1b = (const float*)d_in[2];
    const float* K1w = (const float*)d_in[3];  const float* K1b = (const float*)d_in[4];
    const float* Q1w = (const float*)d_in[5];  const float* Q1b = (const float*)d_in[6];
    const float* V1w = (const float*)d_in[7];  const float* V1b = (const float*)d_in[8];
    const float* E2w = (const float*)d_in[9];  const float* E2b = (const float*)d_in[10];
    const float* K2w = (const float*)d_in[11]; const float* K2b = (const float*)d_in[12];
    const float* Q2w = (const float*)d_in[13]; const float* Q2b = (const float*)d_in[14];
    const float* V2w = (const float*)d_in[15]; const float* V2b = (const float*)d_in[16];
    const float* F1w = (const float*)d_in[17]; const float* F1b = (const float*)d_in[18];
    const float* F2w = (const float*)d_in[19]; const float* F2b = (const float*)d_in[20];

    float* out    = (float*)d_out;
    float* policy = out;                        // [512][64][16]
    float* w1     = out + 512 * 64 * 16;        // [4][512][64][64]
    float* w2     = w1 + 4 * 512 * 64 * 64;     // [4][512][64][64]

    // ws layout (shorts): x1b | x2b | bf16 weights
    short* wsb = (short*)d_ws;
    short* x1b = wsb;
    short* x2b = wsb + 4194304;
    short* wts = wsb + 8388608;
    short* wE1 = wts;            short* wK1 = wts + 131072;
    short* wQ1 = wts + 196608;   short* wV1 = wts + 262144;
    short* wE2 = wts + 278528;   short* wK2 = wts + 344064;
    short* wQ2 = wts + 409600;   short* wV2 = wts + 475136;
    short* wF1 = wts + 491520;   short* wF2 = wts + 499712;

    ConvArgs ca;
    ca.src[0] = E1w; ca.src[1] = K1w; ca.src[2] = Q1w; ca.src[3] = V1w;
    ca.src[4] = E2w; ca.src[5] = K2w; ca.src[6] = Q2w; ca.src[7] = V2w;
    ca.src[8] = F1w; ca.src[9] = F2w;
    ca.end[0] = 32768;  ca.end[1] = 49152;  ca.end[2] = 65536;  ca.end[3] = 69632;
    ca.end[4] = 86016;  ca.end[5] = 102400; ca.end[6] = 118784; ca.end[7] = 122880;
    ca.end[8] = 124928; ca.end[9] = 125184;
    convert_weights_kernel<<<489, 256, 0, stream>>>(ca, wts);

    attn_stage_kernel<256, true><<<2048, 256, 0, stream>>>(
        (const void*)states, wE1, E1b, wK1, K1b, wQ1, Q1b, wV1, V1b, w1, x1b);
    attn_stage_kernel<128, false><<<2048, 256, 0, stream>>>(
        (const void*)x1b, wE2, E2b, wK2, K2b, wQ2, Q2b, wV2, V2b, w2, x2b);
    final_mlp_mfma_kernel<<<512, 256, 0, stream>>>(x2b, wF1, F1b, wF2, F2b, policy);
}